// Round 11
// baseline (1643.592 us; speedup 1.0000x reference)
//
#include <hip/hip_runtime.h>

// Problem constants
#define M_TOK 32000   // B*T tokens
#define DIM   512     // feature dim
#define KCB   1024    // codebook size
#define NQ    8       // quantizer stages
// Tiling: 256x256 block, 8 waves (2Mx4N, wave tile 128x64 of 32x32 MFMAs),
// 16 j-phases of k=32, fused hh/hl/lh: 48 MFMA + 24 b128 reads per phase.
#define BM 256

typedef _Float16 f16x8 __attribute__((ext_vector_type(8)));
typedef _Float16 f16x4 __attribute__((ext_vector_type(4)));
typedef float f32x16 __attribute__((ext_vector_type(16)));

#define SBAR() __builtin_amdgcn_s_barrier()
#define SFENCE() __builtin_amdgcn_sched_barrier(0)
#define WAIT_VM(N) asm volatile("s_waitcnt vmcnt(" #N ")" ::: "memory")

__device__ __forceinline__ void gload_lds16(const void* g, void* l) {
  __builtin_amdgcn_global_load_lds(
      (const __attribute__((address_space(1))) unsigned int*)g,
      (__attribute__((address_space(3))) unsigned int*)l, 16, 0, 0);
}

__device__ __forceinline__ float wave_reduce_sum(float v) {
#pragma unroll
  for (int off = 32; off > 0; off >>= 1) v += __shfl_xor(v, off, 64);
  return v;
}

// Monotone float->uint mapping: a<b (float) <=> fenc(a)<fenc(b) (uint)
__device__ __forceinline__ unsigned int fenc(float f) {
  unsigned int u = __float_as_uint(f);
  return (u & 0x80000000u) ? ~u : (u | 0x80000000u);
}

__device__ __forceinline__ _Float16 hi16(float v) { return (_Float16)v; }
__device__ __forceinline__ _Float16 lo16(float v, _Float16 h) {
  return (_Float16)(v - (float)h);  // Sterbenz-exact then rn — same as R3-R10
}

struct Split4 { f16x4 h, l; };
__device__ __forceinline__ Split4 split4(float4 v) {
  Split4 s;
  s.h[0] = hi16(v.x); s.l[0] = lo16(v.x, s.h[0]);
  s.h[1] = hi16(v.y); s.l[1] = lo16(v.y, s.h[1]);
  s.h[2] = hi16(v.z); s.l[2] = lo16(v.z, s.h[2]);
  s.h[3] = hi16(v.w); s.l[3] = lo16(v.w, s.h[3]);
  return s;
}

// ---------- init: e2, r2, keys, lossCell, and x -> hi/lo fp16 planes ----------
__global__ __launch_bounds__(256) void rvq_init_kernel(
    const float* __restrict__ x, const float* __restrict__ cb,
    float* __restrict__ e2, float* __restrict__ r2,
    unsigned long long* __restrict__ keys, float* __restrict__ lossCell,
    _Float16* __restrict__ ahi, _Float16* __restrict__ alo) {
  if (blockIdx.x == 0 && threadIdx.x == 0) *lossCell = 0.f;
  for (int i = blockIdx.x * 256 + threadIdx.x; i < M_TOK; i += gridDim.x * 256)
    keys[i] = ~0ull;
  int row = blockIdx.x * 4 + (threadIdx.x >> 6);
  int lane = threadIdx.x & 63;
  if (row < NQ * KCB) {
    const float4* s4 = (const float4*)(cb + (size_t)row * DIM);
    float s = 0.f;
    float4 v = s4[lane];
    s += v.x * v.x + v.y * v.y + v.z * v.z + v.w * v.w;
    v = s4[lane + 64];
    s += v.x * v.x + v.y * v.y + v.z * v.z + v.w * v.w;
    s = wave_reduce_sum(s);
    if (lane == 0) e2[row] = s;
  } else {
    int t = row - NQ * KCB;
    if (t >= M_TOK) return;
    const float4* s4 = (const float4*)(x + (size_t)t * DIM);
    float4 v0 = s4[lane], v1 = s4[lane + 64];
    float s = v0.x * v0.x + v0.y * v0.y + v0.z * v0.z + v0.w * v0.w
            + v1.x * v1.x + v1.y * v1.y + v1.z * v1.z + v1.w * v1.w;
    Split4 s0 = split4(v0), s1 = split4(v1);
    size_t base = (size_t)t * DIM + lane * 4;
    *(f16x4*)(ahi + base) = s0.h;
    *(f16x4*)(alo + base) = s0.l;
    *(f16x4*)(ahi + base + 256) = s1.h;
    *(f16x4*)(alo + base + 256) = s1.l;
    s = wave_reduce_sum(s);
    if (lane == 0) r2[t] = s;
  }
}

// ---- pre-split codebooks into ROW-MAJOR hi/lo fp16 planes [8][1024][512] ----
__global__ __launch_bounds__(256) void rvq_split_cb_kernel(
    const float* __restrict__ cb, _Float16* __restrict__ cbh,
    _Float16* __restrict__ cbl) {
  size_t gid = (size_t)blockIdx.x * 256 + threadIdx.x;
  if (gid >= (size_t)NQ * KCB * DIM / 8) return;
  size_t base = gid * 8;
  float4 v0 = *(const float4*)(cb + base);
  float4 v1 = *(const float4*)(cb + base + 4);
  Split4 s0 = split4(v0), s1 = split4(v1);
  *(f16x4*)(cbh + base) = s0.h;
  *(f16x4*)(cbh + base + 4) = s1.h;
  *(f16x4*)(cbl + base) = s0.l;
  *(f16x4*)(cbl + base + 4) = s1.l;
}

// ---- fused distance GEMM + argmin: 32x32 MFMA, imm-offset LDS, run-ptrs ----
__global__ __launch_bounds__(512, 1) void rvq_argmin_kernel(
    const _Float16* __restrict__ ahi,  // [32000][512] residual hi plane
    const _Float16* __restrict__ alo,  // [32000][512] residual lo plane
    const _Float16* __restrict__ cbh,  // [1024][512] stage codebook hi plane
    const _Float16* __restrict__ cbl,  // [1024][512] stage codebook lo plane
    const float* __restrict__ e2,      // [1024]
    const float* __restrict__ r2,      // [32000]
    unsigned long long* __restrict__ keys) {
  // Fragment-slot LDS: slot s = (p*8 + r)*2 + kh holds, for lane l, the 16 B
  // fragment row/col = r*32+(l&31), k = kh*16+(l>>5)*8. 32 slots x 1024 B.
  __shared__ _Float16 As[2][16384];  // 64 KB
  __shared__ _Float16 Bs[2][16384];  // 64 KB

  const int tid = threadIdx.x;
  const int lane = tid & 63, w = tid >> 6;
  const int l31 = lane & 31, l5 = lane >> 5;
  const int wr = w >> 2, wc = w & 3;  // 2(M) x 4(N); wave tile 128x64

  // bijective XCD swizzle for 500 blocks (q=62, r=4): 4 col-siblings adjacent
  const int bid = blockIdx.x;
  const int xcd = bid & 7, org = bid >> 3;
  const int wg = ((xcd < 4) ? xcd * 63 : 252 + (xcd - 4) * 62) + org;
  const int m0 = (wg >> 2) * BM;
  const int nc = wg & 3;
  const int c0 = nc * 256;

  // ---- staging: wave w owns slots w*4..w*4+3 of A and of B; running ptrs ----
  const size_t laneoff = (size_t)l31 * DIM + l5 * 8;
  const _Float16* pA[4];
  const _Float16* pB[4];
#pragma unroll
  for (int i = 0; i < 4; ++i) {
    int s = w * 4 + i;
    int kh = s & 1, r = (s >> 1) & 7, p = s >> 4;
    pA[i] = (p ? alo : ahi) + (size_t)(m0 + r * 32) * DIM + kh * 16 + laneoff;
    pB[i] = (p ? cbl : cbh) + (size_t)(c0 + r * 32) * DIM + kh * 16 + laneoff;
  }
  _Float16* dA0 = &As[0][(w * 4) * 512];
  _Float16* dA1 = &As[1][(w * 4) * 512];
  _Float16* dB0 = &Bs[0][(w * 4) * 512];
  _Float16* dB1 = &Bs[1][(w * 4) * 512];
  auto stageNext = [&](int buf) {  // 8 gloads; bumps pointers by k=32
    _Float16* da = buf ? dA1 : dA0;
    _Float16* db = buf ? dB1 : dB0;
#pragma unroll
    for (int i = 0; i < 4; ++i) {
      gload_lds16(pA[i], da + i * 512);
      pA[i] += 32;
    }
#pragma unroll
    for (int i = 0; i < 4; ++i) {
      gload_lds16(pB[i], db + i * 512);
      pB[i] += 32;
    }
  };

  // read bases: wave-constant + lane*16; all frag offsets are immediates
  const char* Ab0 = (const char*)&As[0][0] + wr * 8192 + lane * 16;
  const char* Ab1 = (const char*)&As[1][0] + wr * 8192 + lane * 16;
  const char* Bb0 = (const char*)&Bs[0][0] + wc * 4096 + lane * 16;
  const char* Bb1 = (const char*)&Bs[1][0] + wc * 4096 + lane * 16;

  f32x16 acc[8];  // [mr'*2 + nf']
#pragma unroll
  for (int a = 0; a < 8; ++a) acc[a] = (f32x16)(0.f);

  stageNext(0);
  for (int j = 0; j < 16; ++j) {
    const int cur = j & 1;
    if (j < 15) {
      stageNext(cur ^ 1);
      WAIT_VM(8);   // tile j landed (per-wave); j+1's 8 stay in flight
    } else {
      WAIT_VM(0);
    }
    SBAR();         // all waves' tile-j loads landed -> buf[cur] published
    SFENCE();
    const char* Ab = cur ? Ab1 : Ab0;
    const char* Bb = cur ? Bb1 : Bb0;
    // B frags up front: [nf'][p][kh], byte off = p*16384 + nf'*2048 + kh*1024
    f16x8 b[2][2][2];
#pragma unroll
    for (int nf = 0; nf < 2; ++nf)
#pragma unroll
      for (int p = 0; p < 2; ++p)
#pragma unroll
        for (int kh = 0; kh < 2; ++kh)
          b[nf][p][kh] = *(const f16x8*)(Bb + p * 16384 + nf * 2048 + kh * 1024);
    __builtin_amdgcn_s_setprio(1);
#pragma unroll
    for (int mr = 0; mr < 4; ++mr) {
      f16x8 a[2][2];  // [p][kh]
#pragma unroll
      for (int p = 0; p < 2; ++p)
#pragma unroll
        for (int kh = 0; kh < 2; ++kh)
          a[p][kh] = *(const f16x8*)(Ab + p * 16384 + mr * 2048 + kh * 1024);
#pragma unroll
      for (int nf = 0; nf < 2; ++nf) {
        f32x16 c = acc[mr * 2 + nf];
        c = __builtin_amdgcn_mfma_f32_32x32x16_f16(a[0][0], b[nf][0][0], c, 0, 0, 0);
        c = __builtin_amdgcn_mfma_f32_32x32x16_f16(a[0][1], b[nf][0][1], c, 0, 0, 0);
        c = __builtin_amdgcn_mfma_f32_32x32x16_f16(a[0][0], b[nf][1][0], c, 0, 0, 0);
        c = __builtin_amdgcn_mfma_f32_32x32x16_f16(a[0][1], b[nf][1][1], c, 0, 0, 0);
        c = __builtin_amdgcn_mfma_f32_32x32x16_f16(a[1][0], b[nf][0][0], c, 0, 0, 0);
        c = __builtin_amdgcn_mfma_f32_32x32x16_f16(a[1][1], b[nf][0][1], c, 0, 0, 0);
        acc[mr * 2 + nf] = c;
      }
    }
    __builtin_amdgcn_s_setprio(0);
    SFENCE();
    SBAR();         // all reads of buf[cur] done before j+2 overwrites it
  }

  // ---- fold: dist = (r2 - 2*dot) + e2; C/D: col=l31, row=(r&3)+8*(r>>2)+4*l5
  const int colb = c0 + wc * 64 + l31;
  const float e2v0 = e2[colb];
  const float e2v1 = e2[colb + 32];
#pragma unroll
  for (int mr = 0; mr < 4; ++mr) {
    const int rowb = m0 + wr * 128 + mr * 32;
    float rv[16];
#pragma unroll
    for (int g = 0; g < 4; ++g) {
      float4 q = *(const float4*)(r2 + rowb + g * 8 + l5 * 4);
      rv[g * 4 + 0] = q.x; rv[g * 4 + 1] = q.y;
      rv[g * 4 + 2] = q.z; rv[g * 4 + 3] = q.w;
    }
#pragma unroll
    for (int reg = 0; reg < 16; ++reg) {
      float d0 = (rv[reg] - 2.f * acc[mr * 2 + 0][reg]) + e2v0;
      float d1 = (rv[reg] - 2.f * acc[mr * 2 + 1][reg]) + e2v1;
      float v = d0;
      int ix = colb;
      if (d1 < v) { v = d1; ix = colb + 32; }  // cols ascending: strict <
#pragma unroll
      for (int off = 16; off; off >>= 1) {     // reduce across the 32 cols
        float ov = __shfl_xor(v, off, 32);
        int oi = __shfl_xor(ix, off, 32);
        if (ov < v || (ov == v && oi < ix)) { v = ov; ix = oi; }
      }
      if (l31 == 0) {
        int tok = rowb + (reg >> 2) * 8 + l5 * 4 + (reg & 3);
        unsigned long long key = ((unsigned long long)fenc(v) << 32) | (unsigned)ix;
        atomicMin(&keys[tok], key);
      }
    }
  }
}

// ------ per-token update: gather, straight-through, loss, next planes ------
__global__ __launch_bounds__(256) void rvq_update_kernel(
    const float* __restrict__ rin, const float* __restrict__ cb,
    unsigned long long* __restrict__ keys,
    float* __restrict__ rout, float* __restrict__ r2out,
    float* __restrict__ idx_out, float* __restrict__ lossCell,
    _Float16* __restrict__ ahi, _Float16* __restrict__ alo) {
  const int wave = threadIdx.x >> 6, lane = threadIdx.x & 63;
  __shared__ float lred[4];
  float lpart = 0.f;
  for (int r = wave; r < 64; r += 4) {
    const int tok = blockIdx.x * 64 + r;
    const unsigned idx = (unsigned)(keys[tok] & 0xffffffffu);
    const float4* rrow = (const float4*)(rin + (size_t)tok * DIM);
    const float4* crow = (const float4*)(cb + (size_t)idx * DIM);
    float4* orow = (float4*)(rout + (size_t)tok * DIM);
    float ssq_t = 0.f, ssq_r = 0.f;
#pragma unroll
    for (int c4 = 0; c4 < 2; ++c4) {
      int c = lane + c4 * 64;
      float4 a = rrow[c], q = crow[c];
      // t = q - r; qst = r + t; r_new = r - qst; loss += t^2  (ref rounding)
      float4 t = make_float4(q.x - a.x, q.y - a.y, q.z - a.z, q.w - a.w);
      float4 qst = make_float4(a.x + t.x, a.y + t.y, a.z + t.z, a.w + t.w);
      float4 rn = make_float4(a.x - qst.x, a.y - qst.y, a.z - qst.z, a.w - qst.w);
      orow[c] = rn;
      Split4 sp = split4(rn);
      *(f16x4*)(ahi + (size_t)tok * DIM + c * 4) = sp.h;
      *(f16x4*)(alo + (size_t)tok * DIM + c * 4) = sp.l;
      ssq_t += t.x * t.x + t.y * t.y + t.z * t.z + t.w * t.w;
      ssq_r += rn.x * rn.x + rn.y * rn.y + rn.z * rn.z + rn.w * rn.w;
    }
    float tot_t = wave_reduce_sum(ssq_t);
    float tot_r = wave_reduce_sum(ssq_r);
    if (lane == 0) {
      idx_out[tok] = (float)idx;
      keys[tok] = ~0ull;  // re-arm for next stage
      r2out[tok] = tot_r;
      lpart += tot_t;
    }
  }
  if (lane == 0) lred[wave] = lpart;
  __syncthreads();
  if (threadIdx.x == 0)
    atomicAdd(lossCell, lred[0] + lred[1] + lred[2] + lred[3]);
}

// ---------------- finalize: out = x - r8, loss scale ----------------
__global__ __launch_bounds__(256) void rvq_finalize_kernel(
    const float* __restrict__ x, float* __restrict__ out,
    const float* __restrict__ lossCell, float* __restrict__ loss_out) {
  size_t i = (size_t)blockIdx.x * 256 + threadIdx.x;
  const size_t n4 = (size_t)M_TOK * DIM / 4;
  if (i < n4) {
    const float4* x4 = (const float4*)x;
    float4* o4 = (float4*)out;
    float4 a = x4[i], r = o4[i];
    o4[i] = make_float4(a.x - r.x, a.y - r.y, a.z - r.z, a.w - r.w);
  }
  if (blockIdx.x == 0 && threadIdx.x == 0) {
    // mean over stages of 1.25*mean_elem(t^2): 1.25 / (8 * 16384000)
    *loss_out = *lossCell * (1.25f / 131072000.f);
  }
}

extern "C" void kernel_launch(void* const* d_in, const int* in_sizes, int n_in,
                              void* d_out, int out_size, void* d_ws, size_t ws_size,
                              hipStream_t stream) {
  const float* x = (const float*)d_in[0];        // [16,2000,512]
  const float* cb = (const float*)d_in[1];       // [8,1024,512]
  float* out = (float*)d_out;                    // quantized region = residual buffer
  float* idx_out = out + (size_t)M_TOK * DIM;    // [8][32000] indices as float
  float* loss_out = idx_out + (size_t)NQ * M_TOK;

  // ws: keys | e2 | r2 | lossCell | cbh (8 MB) | cbl (8 MB) | ahi | alo
  char* wsp = (char*)d_ws;
  unsigned long long* keys = (unsigned long long*)wsp;            // 256000 B
  float* e2 = (float*)(wsp + 262144);
  float* r2 = (float*)(wsp + 294912);
  float* lossCell = (float*)(wsp + 425984);
  _Float16* cbh = (_Float16*)(wsp + 524288);
  _Float16* cbl = (_Float16*)(wsp + 524288 + 8388608);
  _Float16* ahi = (_Float16*)(wsp + 524288 + 16777216);
  _Float16* alo = ahi + (size_t)M_TOK * DIM;

  {
    int rows = NQ * KCB + M_TOK;  // 40192
    rvq_init_kernel<<<(rows + 3) / 4, 256, 0, stream>>>(x, cb, e2, r2, keys,
                                                        lossCell, ahi, alo);
    int n8 = NQ * KCB * DIM / 8;  // 524288
    rvq_split_cb_kernel<<<n8 / 256, 256, 0, stream>>>(cb, cbh, cbl);
  }
  float* resbuf = out;
  for (int s = 0; s < NQ; ++s) {
    const float* rin = (s == 0) ? x : resbuf;
    rvq_argmin_kernel<<<(M_TOK / BM) * 4, 512, 0, stream>>>(
        ahi, alo, cbh + (size_t)s * KCB * DIM, cbl + (size_t)s * KCB * DIM,
        e2 + s * KCB, r2, keys);
    rvq_update_kernel<<<M_TOK / 64, 256, 0, stream>>>(
        rin, cb + (size_t)s * KCB * DIM, keys, resbuf, r2,
        idx_out + (size_t)s * M_TOK, lossCell, ahi, alo);
  }
  rvq_finalize_kernel<<<(M_TOK * DIM / 4 + 255) / 256, 256, 0, stream>>>(
      x, out, lossCell, loss_out);
}